// Round 4
// baseline (83.618 us; speedup 1.0000x reference)
//
#include <hip/hip_runtime.h>
#include <hip/hip_bf16.h>
#include <math.h>

#define NPAIR 4096       // N = B*S
#define D 128
#define TWO_N 8192
#define NSLAB 32         // 8 jc-slabs x 4 waves, race-free partial rows
// Rb rows pre-scaled by ALPHA = sqrt(2*log2(e)): MFMA acc == 2*log2(e)*sim,
// so exp(2*sim) == exp2(acc) -> a single raw v_exp_f32 in the epilogue.
#define ALPHA 1.6986436f

typedef float f32x4 __attribute__((ext_vector_type(4)));
typedef int i32x8 __attribute__((ext_vector_type(8)));

__device__ __forceinline__ i32x8 mk8(uint4 lo, uint4 hi) {
    return (i32x8){(int)lo.x, (int)lo.y, (int)lo.z, (int)lo.w,
                   (int)hi.x, (int)hi.y, (int)hi.z, (int)hi.w};
}

// 512 blocks x 256 threads; half-wave h (32 lanes) handles pair-row
// k = blockIdx*8 + h, 4 elems/lane via float4. Emits ALPHA-scaled fp8 e4m3
// rows, PLAIN ROW-MAJOR, one dword store per lane per row.
// pos[] stays exact fp32. Zero-inits out[0].  [PASSED r1/r3]
__global__ __launch_bounds__(256) void norm_kernel(const float* __restrict__ zi,
                                                   const float* __restrict__ zj,
                                                   unsigned char* __restrict__ Rb,
                                                   float* __restrict__ pos,
                                                   float* __restrict__ out) {
    if (blockIdx.x == 0 && threadIdx.x == 0) out[0] = 0.f;
    int k = blockIdx.x * 8 + (threadIdx.x >> 5);
    int t = threadIdx.x & 31;                 // 4 elems each
    const float4 a = *(const float4*)(zi + k * D + 4 * t);
    const float4 b = *(const float4*)(zj + k * D + 4 * t);
    float si = a.x * a.x + a.y * a.y + a.z * a.z + a.w * a.w;
    float sj = b.x * b.x + b.y * b.y + b.z * b.z + b.w * b.w;
    float dt = a.x * b.x + a.y * b.y + a.z * b.z + a.w * b.w;
    #pragma unroll
    for (int m = 1; m < 32; m <<= 1) {        // reduce within the 32-lane row
        si += __shfl_xor(si, m, 32);
        sj += __shfl_xor(sj, m, 32);
        dt += __shfl_xor(dt, m, 32);
    }
    float ii = 1.0f / fmaxf(sqrtf(si), 1e-12f);
    float ij = 1.0f / fmaxf(sqrtf(sj), 1e-12f);
    if (t == 0) pos[k] = dt * ii * ij;        // exact (unscaled) positive sim
    ii *= ALPHA; ij *= ALPHA;
    int r0 = __builtin_amdgcn_cvt_pk_fp8_f32(a.x * ii, a.y * ii, 0, false);
    r0 = __builtin_amdgcn_cvt_pk_fp8_f32(a.z * ii, a.w * ii, r0, true);
    *(unsigned int*)(Rb + (size_t)k * 128 + 4 * t) = (unsigned int)r0;
    int r1 = __builtin_amdgcn_cvt_pk_fp8_f32(b.x * ij, b.y * ij, 0, false);
    r1 = __builtin_amdgcn_cvt_pk_fp8_f32(b.z * ij, b.w * ij, r1, true);
    *(unsigned int*)(Rb + (size_t)(k + NPAIR) * 128 + 4 * t) = (unsigned int)r1;
}

// MX-scaled fp8 MFMA (K=128 in ONE instruction). 1024 blocks: bi = b>>3
// (64-row stripe), jc = b&7 (1024-col slab, 16 jt tiles of 64 cols).
// ZERO LDS, ZERO BARRIERS: per-wave B panel (16 cols x 128B) == 32B/lane ==
// the MFMA B fragment, gathered straight into registers (2x dwordx4/lane/jt).
// __launch_bounds__(256,4) caps VGPR at 128 -> 4 waves/SIMD (r3 dropped the
// cap and regressed ~6us: unbounded alloc crosses the 128-VGPR occupancy
// step, halving resident waves). Live state ~115 VGPR -> fits, no spill
// (r1's spill came from acc[2][4]+lambda, both gone). 3-deep named-register
// pipeline (24 VGPR): jt body ~300cy vs L2 latency ~200-300cy, so 2-deep was
// marginal. Same-jt epilogue dataflow (r2's cross-jt WAR stagger -> inf).
__global__ __launch_bounds__(256, 4) void simexp_kernel(const unsigned char* __restrict__ Rb,
                                                        float* __restrict__ rspart) {
    const int bi = blockIdx.x >> 3;      // 0..127 (64-row stripe)
    const int jc = blockIdx.x & 7;       // 0..7  (1024-col slab)
    const int tid = threadIdx.x;
    const int wave = tid >> 6, lane = tid & 63;
    const int rp = lane & 15, q = lane >> 4;

    // A fragments: row = bi*64 + rt*16 + rp; lane's k [q*32, q*32+32).
    i32x8 afr[4];                        // [rt]
    {
        const unsigned char* Ab = Rb + (size_t)(bi * 64 + rp) * 128 + q * 32;
        #pragma unroll
        for (int rt = 0; rt < 4; ++rt) {
            uint4 h0 = *(const uint4*)(Ab + rt * 16 * 128);
            uint4 h1 = *(const uint4*)(Ab + rt * 16 * 128 + 16);
            afr[rt] = mk8(h0, h1);
        }
    }

    // B fragment source: lane (rp,q) needs col jc*1024 + jt*64 + wave*16 + rp,
    // bytes [q*32, q*32+32) of that 128B row. uint4 index: jt*512 (+1).
    const uint4* gB = (const uint4*)(Rb + (size_t)(jc * 1024 + wave * 16 + rp) * 128 + q * 32);

    float rs[16];
    #pragma unroll
    for (int i = 0; i < 16; ++i) rs[i] = 0.f;

    const int diagjt = bi - 16 * jc;     // jt tile holding the diagonal (may be OOR)
    const int co = wave * 16 + rp;       // this lane's tile-local output col

    // 3-deep register pipeline: p0 = panel jt, p1 = jt+1, p2 = jt+2
    uint4 p0a = gB[0],    p0b = gB[1];
    uint4 p1a = gB[512],  p1b = gB[513];
    uint4 p2a = gB[1024], p2b = gB[1025];

    #pragma unroll
    for (int jt = 0; jt < 16; ++jt) {
        i32x8 bfr = mk8(p0a, p0b);
        p0a = p1a; p0b = p1b;            // rotates: pure renames under unroll
        p1a = p2a; p1b = p2b;
        if (jt < 13) {                   // prefetch panel jt+3 (issue-early)
            p2a = gB[(jt + 3) * 512];
            p2b = gB[(jt + 3) * 512 + 1];
        }

        f32x4 acc[4];
        __builtin_amdgcn_s_setprio(1);
        #pragma unroll
        for (int rt = 0; rt < 4; ++rt) {
            f32x4 z = {0.f, 0.f, 0.f, 0.f};
            acc[rt] = __builtin_amdgcn_mfma_scale_f32_16x16x128_f8f6f4(
                afr[rt], bfr, z,
                0, 0,                     // cbsz=fp8(e4m3), blgp=fp8(e4m3)
                0, 0x7F7F7F7F,            // A scale opsel, scale = 1.0
                0, 0x7F7F7F7F);           // B scale opsel, scale = 1.0
        }
        __builtin_amdgcn_s_setprio(0);

        // same-jt epilogue (proven dataflow): exp2 of acc -> rs
        if (jt == diagjt) {              // the one jt tile holding the diagonal
            #pragma unroll
            for (int rt = 0; rt < 4; ++rt)
                #pragma unroll
                for (int r = 0; r < 4; ++r) {
                    int ro = rt * 16 + q * 4 + r;
                    float e = __builtin_amdgcn_exp2f(acc[rt][r]);
                    rs[rt * 4 + r] += (ro == co) ? 0.f : e;
                }
        } else {
            #pragma unroll
            for (int rt = 0; rt < 4; ++rt)
                #pragma unroll
                for (int r = 0; r < 4; ++r)
                    rs[rt * 4 + r] += __builtin_amdgcn_exp2f(acc[rt][r]);
        }
    }

    // Reduce each reg across the 16 rp lanes; rp==0 stores its 16 rows.
    #pragma unroll
    for (int i = 0; i < 16; ++i) {
        float v = rs[i];
        v += __shfl_xor(v, 1, 64);
        v += __shfl_xor(v, 2, 64);
        v += __shfl_xor(v, 4, 64);
        v += __shfl_xor(v, 8, 64);
        rs[i] = v;
    }
    if (rp == 0) {
        const int slab = jc * 4 + wave;
        const int rowb = bi * 64 + q * 4;
        // rspart layout [row][slab] so finalize reads are float4-vectorizable
        #pragma unroll
        for (int rt = 0; rt < 4; ++rt)
            #pragma unroll
            for (int r = 0; r < 4; ++r)
                rspart[(size_t)(rowb + rt * 16 + r) * NSLAB + slab] = rs[rt * 4 + r];
    }
}

// 64 blocks x 128 threads; each thread owns one row: 8x float4 loads of its
// 32 slab partials, then log/exp epilogue; one atomicAdd per block.
// [PASSED r1/r3]
__global__ __launch_bounds__(128) void finalize_kernel(const float* __restrict__ rspart,
                                                       const float* __restrict__ pos,
                                                       float* __restrict__ out) {
    __shared__ float red[2];
    int tid = threadIdx.x;
    int k = blockIdx.x * 128 + tid;
    const f32x4* v = (const f32x4*)(rspart + (size_t)k * NSLAB);
    f32x4 s = v[0];
    #pragma unroll
    for (int p = 1; p < 8; ++p) s += v[p];
    float rsum = s.x + s.y + s.z + s.w;
    float ps = pos[k & (NPAIR - 1)];
    float p2 = ps + ps;
    float local = logf(rsum + __expf(p2)) - p2;
    #pragma unroll
    for (int m = 1; m < 64; m <<= 1) local += __shfl_xor(local, m, 64);
    if ((tid & 63) == 0) red[tid >> 6] = local;
    __syncthreads();
    if (tid == 0) atomicAdd(out, (red[0] + red[1]) * (1.0f / (float)TWO_N));
}

extern "C" void kernel_launch(void* const* d_in, const int* in_sizes, int n_in,
                              void* d_out, int out_size, void* d_ws, size_t ws_size,
                              hipStream_t stream) {
    const float* zi = (const float*)d_in[0];
    const float* zj = (const float*)d_in[1];
    char* ws = (char*)d_ws;
    unsigned char* Rb = (unsigned char*)ws;                         // 1 MB fp8 rows
    float* rspart = (float*)(ws + 1 * 1024 * 1024);                 // 8192*32*4 = 1 MB
    float* pos = (float*)(ws + 2 * 1024 * 1024);                    // 16 KB

    norm_kernel<<<NPAIR / 8, 256, 0, stream>>>(zi, zj, Rb, pos, (float*)d_out);
    simexp_kernel<<<128 * 8, 256, 0, stream>>>(Rb, rspart);
    finalize_kernel<<<64, 128, 0, stream>>>(rspart, pos, (float*)d_out);
}

// Round 5
// 81.725 us; speedup vs baseline: 1.0232x; 1.0232x over previous
//
#include <hip/hip_runtime.h>
#include <hip/hip_bf16.h>
#include <math.h>

#define NPAIR 4096       // N = B*S
#define D 128
#define TWO_N 8192
#define NSLAB 32         // 8 jc-slabs x 4 waves, race-free partial rows
// Rb rows pre-scaled by ALPHA = sqrt(2*log2(e)): MFMA acc == 2*log2(e)*sim,
// so exp(2*sim) == exp2(acc) -> a single raw v_exp_f32 in the epilogue.
#define ALPHA 1.6986436f

typedef float f32x4 __attribute__((ext_vector_type(4)));
typedef int i32x8 __attribute__((ext_vector_type(8)));

__device__ __forceinline__ void async_ld16(void* lds, const void* g) {
    // async global->LDS DMA, 16B/lane; LDS dest = wave-uniform base + lane*16
    __builtin_amdgcn_global_load_lds(
        (__attribute__((address_space(1))) const unsigned int*)g,
        (__attribute__((address_space(3))) unsigned int*)lds, 16, 0, 0);
}

__device__ __forceinline__ i32x8 mk8(uint4 lo, uint4 hi) {
    return (i32x8){(int)lo.x, (int)lo.y, (int)lo.z, (int)lo.w,
                   (int)hi.x, (int)hi.y, (int)hi.z, (int)hi.w};
}

// 512 blocks x 256 threads; half-wave h (32 lanes) handles pair-row
// k = blockIdx*8 + h, 4 elems/lane via float4. Emits ALPHA-scaled fp8 e4m3
// rows, PLAIN ROW-MAJOR, one dword store per lane per row. Also zeroes
// colpart (8192 floats) for simexp's transpose-side atomics (stream-ordered).
// pos[] stays exact fp32. Zero-inits out[0].  [core PASSED r1/r3/r4]
__global__ __launch_bounds__(256) void norm_kernel(const float* __restrict__ zi,
                                                   const float* __restrict__ zj,
                                                   unsigned char* __restrict__ Rb,
                                                   float* __restrict__ pos,
                                                   float* __restrict__ colpart,
                                                   float* __restrict__ out) {
    if (blockIdx.x == 0 && threadIdx.x == 0) out[0] = 0.f;
    if (blockIdx.x < 32) colpart[blockIdx.x * 256 + threadIdx.x] = 0.f;
    int k = blockIdx.x * 8 + (threadIdx.x >> 5);
    int t = threadIdx.x & 31;                 // 4 elems each
    const float4 a = *(const float4*)(zi + k * D + 4 * t);
    const float4 b = *(const float4*)(zj + k * D + 4 * t);
    float si = a.x * a.x + a.y * a.y + a.z * a.z + a.w * a.w;
    float sj = b.x * b.x + b.y * b.y + b.z * b.z + b.w * b.w;
    float dt = a.x * b.x + a.y * b.y + a.z * b.z + a.w * b.w;
    #pragma unroll
    for (int m = 1; m < 32; m <<= 1) {        // reduce within the 32-lane row
        si += __shfl_xor(si, m, 32);
        sj += __shfl_xor(sj, m, 32);
        dt += __shfl_xor(dt, m, 32);
    }
    float ii = 1.0f / fmaxf(sqrtf(si), 1e-12f);
    float ij = 1.0f / fmaxf(sqrtf(sj), 1e-12f);
    if (t == 0) pos[k] = dt * ii * ij;        // exact (unscaled) positive sim
    ii *= ALPHA; ij *= ALPHA;
    int r0 = __builtin_amdgcn_cvt_pk_fp8_f32(a.x * ii, a.y * ii, 0, false);
    r0 = __builtin_amdgcn_cvt_pk_fp8_f32(a.z * ii, a.w * ii, r0, true);
    *(unsigned int*)(Rb + (size_t)k * 128 + 4 * t) = (unsigned int)r0;
    int r1 = __builtin_amdgcn_cvt_pk_fp8_f32(b.x * ij, b.y * ij, 0, false);
    r1 = __builtin_amdgcn_cvt_pk_fp8_f32(b.z * ij, b.w * ij, r1, true);
    *(unsigned int*)(Rb + (size_t)(k + NPAIR) * 128 + 4 * t) = (unsigned int)r1;
}

// ROUND-0 PROVEN STRUCTURE (LDS triple-buffer DMA, vmcnt(2), XOR slots) +
// SYMMETRY HALVING at slab granularity. sim is symmetric: keep block (bi,jc)
// iff jc >= bi>>4 (576/1024 blocks; dropped blocks early-exit ~20cy).
//  - diag-slab blocks (jc == bi>>4): exact r0 behavior — row-sums over the
//    full slab (incl. within-slab below-diag cols), diagonal element zeroed.
//  - strictly-above blocks (jc > bi>>4): row-sums PLUS column partials: each
//    lane's output col co is FIXED across its 16 acc elems, so the tile col
//    sum = 16 adds + shfl_xor(16,32) + one atomicAdd by q==0 lanes (~30cy/jt).
//    Transposes of these tiles are exactly the below-diag-slab entries of
//    every row: disjoint + complete coverage (row r direct sums cover slabs
//    >= r>>10, colpart covers slabs < r>>10).
// MFMA+exp work -> 56.25% of full grid.
__global__ __launch_bounds__(256, 4) void simexp_kernel(const unsigned char* __restrict__ Rb,
                                                        float* __restrict__ rspart,
                                                        float* __restrict__ colpart) {
    const int bi = blockIdx.x >> 3;      // 0..127 (64-row stripe)
    const int jc = blockIdx.x & 7;       // 0..7  (1024-col slab)
    const int s = bi >> 4;               // stripe's diagonal slab
    if (jc < s) return;                  // below-diagonal slab: transpose-covered
    const bool emitcol = (jc > s);

    __shared__ uint4 Bs[4][3][128];      // [wave][buf][16 cols x 8 pieces] 2KB/buf
    const int tid = threadIdx.x;
    const int wave = tid >> 6, lane = tid & 63;
    const int rp = lane & 15, q = lane >> 4;

    // A fragments: row = bi*64 + rt*16 + rp; lane's k [q*32, q*32+32).
    i32x8 afr[4];                        // [rt]
    {
        const unsigned char* Ab = Rb + (size_t)(bi * 64 + rp) * 128 + q * 32;
        #pragma unroll
        for (int rt = 0; rt < 4; ++rt) {
            uint4 h0 = *(const uint4*)(Ab + rt * 16 * 128);
            uint4 h1 = *(const uint4*)(Ab + rt * 16 * 128 + 16);
            afr[rt] = mk8(h0, h1);
        }
    }

    // Wave-private B panel: cols jc*1024 + jt*64 + wave*16 + [0,16), 128B/col,
    // 2 DMAs/jt (8 cols each). DMA d, lane l: col cr = d*8 + (l>>3), stored
    // piece p' = l&7, global piece p = p' ^ (cr&7)  [slot = cr*8 + (p^(cr&7))].
    const unsigned char* gslab = Rb + (size_t)(jc * 1024 + wave * 16) * 128;
    char* lpanel = (char*)&Bs[wave][0][0];
    const int laneoff = (lane >> 3) * 128 + (((lane & 7) ^ ((lane >> 3) & 7)) << 4);

    float rs[16];
    #pragma unroll
    for (int i = 0; i < 16; ++i) rs[i] = 0.f;

    // prefetch jt=0 (buf0) and jt=1 (buf1): 4 DMAs outstanding
    #pragma unroll
    for (int j = 0; j < 2; ++j)
        #pragma unroll
        for (int d = 0; d < 2; ++d)
            async_ld16(lpanel + j * 2048 + d * 1024,
                       gslab + j * 8192 + d * 1024 + laneoff);

    const int diagbase = bi * 64 - jc * 1024;   // diag col offset in slab
    const int slot0 = rp * 8;
    const int sw = rp & 7;

    #pragma unroll
    for (int jt = 0; jt < 16; ++jt) {
        // Wait only for the OLDEST panel (this jt's 2 DMAs); next stays in flight.
        if (jt < 14) __builtin_amdgcn_s_waitcnt(0x0F72);   // vmcnt(2)
        else         __builtin_amdgcn_s_waitcnt(0x0F70);   // vmcnt(0)

        const int cur = jt % 3;
        const uint4* P = &Bs[wave][cur][0];
        // lane needs col rp pieces 2q (k low half) and 2q+1 (k high half)
        uint4 u0 = P[slot0 + ((q * 2 + 0) ^ sw)];
        uint4 u1 = P[slot0 + ((q * 2 + 1) ^ sw)];
        i32x8 bfr = mk8(u0, u1);

        if (jt < 14) {                   // prefetch jt+2 into buf (jt+2)%3
            const int nb = (jt + 2) % 3;
            #pragma unroll
            for (int d = 0; d < 2; ++d)
                async_ld16(lpanel + nb * 2048 + d * 1024,
                           gslab + (jt + 2) * 8192 + d * 1024 + laneoff);
        }

        f32x4 acc[4] = {};
        #pragma unroll
        for (int rt = 0; rt < 4; ++rt)
            acc[rt] = __builtin_amdgcn_mfma_scale_f32_16x16x128_f8f6f4(
                afr[rt], bfr, acc[rt],
                0, 0,                     // cbsz=fp8(e4m3), blgp=fp8(e4m3)
                0, 0x7F7F7F7F,            // A scale opsel, scale = 1.0
                0, 0x7F7F7F7F);           // B scale opsel, scale = 1.0

        // D layout: col(tile-local) = wave*16 + rp, row = rt*16 + q*4 + r
        if (jt * 64 == diagbase) {       // the one jt tile holding the diagonal
            #pragma unroll
            for (int rt = 0; rt < 4; ++rt)
                #pragma unroll
                for (int r = 0; r < 4; ++r) {
                    int ro = rt * 16 + q * 4 + r;
                    int co = wave * 16 + rp;
                    float e = __builtin_amdgcn_exp2f(acc[rt][r]);
                    rs[rt * 4 + r] += (ro == co) ? 0.f : e;
                }
        } else if (emitcol) {
            float csum = 0.f;
            #pragma unroll
            for (int rt = 0; rt < 4; ++rt)
                #pragma unroll
                for (int r = 0; r < 4; ++r) {
                    float e = __builtin_amdgcn_exp2f(acc[rt][r]);
                    rs[rt * 4 + r] += e;
                    csum += e;
                }
            // col co total over the tile's 64 rows: reduce across q
            csum += __shfl_xor(csum, 16, 64);
            csum += __shfl_xor(csum, 32, 64);
            if (q == 0)
                atomicAdd(colpart + jc * 1024 + jt * 64 + wave * 16 + rp, csum);
        } else {
            #pragma unroll
            for (int rt = 0; rt < 4; ++rt)
                #pragma unroll
                for (int r = 0; r < 4; ++r)
                    rs[rt * 4 + r] += __builtin_amdgcn_exp2f(acc[rt][r]);
        }
    }

    // Reduce each reg across the 16 rp lanes; rp==0 stores its 16 rows.
    #pragma unroll
    for (int i = 0; i < 16; ++i) {
        float v = rs[i];
        v += __shfl_xor(v, 1, 64);
        v += __shfl_xor(v, 2, 64);
        v += __shfl_xor(v, 4, 64);
        v += __shfl_xor(v, 8, 64);
        rs[i] = v;
    }
    if (rp == 0) {
        const int slab = jc * 4 + wave;
        const int rowb = bi * 64 + q * 4;
        // rspart layout [row][slab] so finalize reads are float4-vectorizable
        #pragma unroll
        for (int rt = 0; rt < 4; ++rt)
            #pragma unroll
            for (int r = 0; r < 4; ++r)
                rspart[(size_t)(rowb + rt * 16 + r) * NSLAB + slab] = rs[rt * 4 + r];
    }
}

// 64 blocks x 128 threads; each thread owns one row. Only slabs jc >= s
// (s = row>>10) were written (lower ones hold workspace poison) -> sum
// float4 groups [s, 8), then add colpart[row] (the below-diag-slab mass).
__global__ __launch_bounds__(128) void finalize_kernel(const float* __restrict__ rspart,
                                                       const float* __restrict__ colpart,
                                                       const float* __restrict__ pos,
                                                       float* __restrict__ out) {
    __shared__ float red[2];
    int tid = threadIdx.x;
    int k = blockIdx.x * 128 + tid;
    int s = k >> 10;                     // uniform per block (128 rows/block)
    const f32x4* v = (const f32x4*)(rspart + (size_t)k * NSLAB);
    f32x4 sv = {0.f, 0.f, 0.f, 0.f};
    for (int p4 = s; p4 < 8; ++p4) sv += v[p4];   // one float4 per jc slab
    float rsum = sv.x + sv.y + sv.z + sv.w + colpart[k];
    float ps = pos[k & (NPAIR - 1)];
    float p2 = ps + ps;
    float local = logf(rsum + __expf(p2)) - p2;
    #pragma unroll
    for (int m = 1; m < 64; m <<= 1) local += __shfl_xor(local, m, 64);
    if ((tid & 63) == 0) red[tid >> 6] = local;
    __syncthreads();
    if (tid == 0) atomicAdd(out, (red[0] + red[1]) * (1.0f / (float)TWO_N));
}

extern "C" void kernel_launch(void* const* d_in, const int* in_sizes, int n_in,
                              void* d_out, int out_size, void* d_ws, size_t ws_size,
                              hipStream_t stream) {
    const float* zi = (const float*)d_in[0];
    const float* zj = (const float*)d_in[1];
    char* ws = (char*)d_ws;
    unsigned char* Rb = (unsigned char*)ws;                         // 1 MB fp8 rows
    float* rspart = (float*)(ws + 1 * 1024 * 1024);                 // 8192*32*4 = 1 MB
    float* pos = (float*)(ws + 2 * 1024 * 1024);                    // 16 KB
    float* colpart = (float*)(ws + 2 * 1024 * 1024 + 16 * 1024);    // 32 KB

    norm_kernel<<<NPAIR / 8, 256, 0, stream>>>(zi, zj, Rb, pos, colpart, (float*)d_out);
    simexp_kernel<<<128 * 8, 256, 0, stream>>>(Rb, rspart, colpart);
    finalize_kernel<<<64, 128, 0, stream>>>(rspart, colpart, pos, (float*)d_out);
}